// Round 6
// baseline (6775.791 us; speedup 1.0000x reference)
//
#include <hip/hip_runtime.h>
#include <hip/hip_fp16.h>

#define NN 100000
#define IN_CH 128
#define HID 32
#define OUT_CH 64
#define N_LAYERS 16
#define NB1 2048            // agg-pass blocks (4 waves each -> 8192 waves)
#define EPS_MSG 1e-7f
#define EPS_SM 1e-16f
#define EPS_BN 1e-5f

// ---------------- CSR build ----------------

__global__ void k_hist(const int* __restrict__ dst, int* __restrict__ counts, int E) {
    int i = blockIdx.x * 256 + threadIdx.x;
    if (i < E) atomicAdd(&counts[dst[i]], 1);
}

__global__ void k_scan1(const int* __restrict__ counts, int* __restrict__ rowptr,
                        int* __restrict__ bsum, int n) {
    __shared__ int sh[1024];
    int t = threadIdx.x;
    int i = blockIdx.x * 1024 + t;
    int v = (i < n) ? counts[i] : 0;
    sh[t] = v;
    __syncthreads();
    for (int off = 1; off < 1024; off <<= 1) {
        int tmp = (t >= off) ? sh[t - off] : 0;
        __syncthreads();
        sh[t] += tmp;
        __syncthreads();
    }
    if (i < n) rowptr[i] = sh[t] - v;   // exclusive within chunk
    if (t == 1023) bsum[blockIdx.x] = sh[1023];
}

__global__ void k_scan2(int* __restrict__ bsum, int nb) {
    if (threadIdx.x == 0 && blockIdx.x == 0) {
        int acc = 0;
        for (int b = 0; b < nb; b++) { int v = bsum[b]; bsum[b] = acc; acc += v; }
    }
}

__global__ void k_scan3(int* __restrict__ rowptr, int* __restrict__ cursor,
                        const int* __restrict__ bsum, int n, int E) {
    int i = blockIdx.x * 256 + threadIdx.x;
    if (i < n) {
        int r = rowptr[i] + bsum[i >> 10];
        rowptr[i] = r;
        cursor[i] = r;
    }
    if (i == 0) rowptr[n] = E;
}

__global__ void k_scatter(const int* __restrict__ src, const int* __restrict__ dst,
                          int* __restrict__ cursor, int* __restrict__ col, int E) {
    int i = blockIdx.x * 256 + threadIdx.x;
    if (i < E) {
        int d = dst[i];
        int p = atomicAdd(&cursor[d], 1);
        col[p] = src[i];
    }
}

// ---------------- input projection: h0 = x @ w0 + b0 (+ fp16 chunked messages) ----------------

__global__ __launch_bounds__(256) void k0(const float* __restrict__ x,
                                          const float* __restrict__ w0,
                                          const float* __restrict__ b0,
                                          float* __restrict__ h,
                                          __half* __restrict__ mA,
                                          __half* __restrict__ mB) {
    __shared__ float ws[IN_CH * HID];   // 16 KB
    __shared__ float xs[8][IN_CH];      // 4 KB
    int tid = threadIdx.x, c = tid & 31, g = tid >> 5;
    for (int k = tid; k < IN_CH * HID; k += 256) ws[k] = w0[k];
    int d = blockIdx.x * 8 + g;
    float4 xv = ((const float4*)(x + (size_t)d * IN_CH))[c];
    ((float4*)xs[g])[c] = xv;
    __syncthreads();
    float acc = b0[c];
#pragma unroll 16
    for (int k = 0; k < IN_CH; k++) acc += xs[g][k] * ws[k * HID + c];
    h[(size_t)d * HID + c] = acc;
    __half mv = __float2half(fmaxf(acc, 0.f));      // relu(h); +eps added at gather
    if (c < 16) mA[(size_t)d * 16 + c] = mv;
    else        mB[(size_t)d * 16 + (c - 16)] = mv;
}

// ---------------- softmax-agg pass over ONE 16-channel chunk ----------------
// One node per full wave: 64 lanes = 16 channels x 4 edge-slots. The gathered
// array mc is 3.2 MB -> resident in each XCD's 4 MB L2 (round-6 theory).
// Zero LDS; __launch_bounds__(256,8) pins 32 waves/CU.

__global__ __launch_bounds__(256, 8) void k_aggp(const float* __restrict__ h,
                                                 const __half* __restrict__ mc,
                                                 const int* __restrict__ rowptr,
                                                 const int* __restrict__ col,
                                                 float* __restrict__ oc,
                                                 int coff) {
    int tid = threadIdx.x;
    int lane = tid & 63;
    int c = lane & 15;                     // channel within chunk
    int eslot = lane >> 4;                 // 0..3: edge sub-slot
    int wid = (blockIdx.x * 256 + tid) >> 6;
    const int nwaves = NB1 * 4;

    for (int d = wid; d < NN; d += nwaves) {
        int r0 = rowptr[d], r1 = rowptr[d + 1];   // wave-uniform -> scalar loads
        float den = 0.f, num = 0.f;
        for (int e0 = r0; e0 < r1; e0 += 32) {
            int colw = col[e0 + (lane & 31)];     // 32-edge window, coalesced
            int nb = r1 - e0; if (nb > 32) nb = 32;
            float vv[8];
#pragma unroll
            for (int j = 0; j < 8; j++) {         // 8 instrs x 4 edges in flight
                int s = __shfl(colw, j * 4 + eslot, 64);
                vv[j] = __half2float(mc[(size_t)s * 16 + c]);
            }
#pragma unroll
            for (int j = 0; j < 8; j++) {
                float v = vv[j] + EPS_MSG;
                float ev = __expf(v);             // bounded: no max-subtraction
                bool ok = (j * 4 + eslot) < nb;
                den += ok ? ev : 0.f;
                num += ok ? ev * v : 0.f;
            }
        }
        // reduce across the 4 edge-slots (lanes c, c+16, c+32, c+48)
        den += __shfl_xor(den, 16, 64); num += __shfl_xor(num, 16, 64);
        den += __shfl_xor(den, 32, 64); num += __shfl_xor(num, 32, 64);
        if (eslot == 0) {
            float res = h[(size_t)d * HID + coff + c];
            oc[(size_t)d * 16 + c] = num / (den + EPS_SM) + res;
        }
    }
}

// ---------------- lin1 + BN partial sums (streaming) ----------------

__global__ __launch_bounds__(256) void k_lin1(const float* __restrict__ oA,
                                              const float* __restrict__ oB,
                                              const float* __restrict__ w1,
                                              const float* __restrict__ b1,
                                              float* __restrict__ z,
                                              float* __restrict__ zsum,
                                              int layer) {
    __shared__ float w1s[HID * 64];   // 8 KB
    __shared__ float b1s[64];
    __shared__ float outs[8][HID];
    __shared__ float red[256];
    int tid = threadIdx.x, c = tid & 31, g = tid >> 5;
    for (int k = tid; k < HID * 64; k += 256) w1s[k] = w1[layer * (HID * 64) + k];
    if (tid < 64) b1s[tid] = b1[layer * 64 + tid];
    int d = blockIdx.x * 8 + g;
    outs[g][c] = (c < 16) ? oA[(size_t)d * 16 + c] : oB[(size_t)d * 16 + (c - 16)];
    __syncthreads();
    float z0 = b1s[c], z1 = b1s[c + 32];
#pragma unroll
    for (int k = 0; k < HID; k++) {
        float o = outs[g][k];
        z0 += o * w1s[k * 64 + c];
        z1 += o * w1s[k * 64 + c + 32];
    }
    z[(size_t)d * 64 + c] = z0;
    z[(size_t)d * 64 + 32 + c] = z1;

    // BN partials: block reduce then slotted atomics (16 slots/channel)
    float* acc = zsum + layer * 2048;
    int slot = blockIdx.x & 15;
    red[tid] = z0; __syncthreads();
    if (tid < 32) { float a = 0; for (int g2 = 0; g2 < 8; g2++) a += red[g2 * 32 + tid]; atomicAdd(&acc[tid * 16 + slot], a); }
    __syncthreads();
    red[tid] = z1; __syncthreads();
    if (tid < 32) { float a = 0; for (int g2 = 0; g2 < 8; g2++) a += red[g2 * 32 + tid]; atomicAdd(&acc[(32 + tid) * 16 + slot], a); }
    __syncthreads();
    red[tid] = z0 * z0; __syncthreads();
    if (tid < 32) { float a = 0; for (int g2 = 0; g2 < 8; g2++) a += red[g2 * 32 + tid]; atomicAdd(&acc[(64 + tid) * 16 + slot], a); }
    __syncthreads();
    red[tid] = z1 * z1; __syncthreads();
    if (tid < 32) { float a = 0; for (int g2 = 0; g2 < 8; g2++) a += red[g2 * 32 + tid]; atomicAdd(&acc[(96 + tid) * 16 + slot], a); }
}

// ---------------- BN apply + relu + lin2 + relu (+ fp16 chunked messages) ----------------

__global__ __launch_bounds__(256) void k_bn2(const float* __restrict__ z,
                                             const float* __restrict__ zsum,
                                             const float* __restrict__ gamma,
                                             const float* __restrict__ beta,
                                             const float* __restrict__ w2,
                                             const float* __restrict__ b2,
                                             float* __restrict__ hout,
                                             __half* __restrict__ mA,
                                             __half* __restrict__ mB,
                                             int layer) {
    __shared__ float w2s[64 * HID];   // 8 KB
    __shared__ float zs[8][64];
    __shared__ float scs[64], shs[64];
    int tid = threadIdx.x, c = tid & 31, g = tid >> 5;
    for (int k = tid; k < 64 * HID; k += 256) w2s[k] = w2[layer * (64 * HID) + k];
    if (tid < 64) {
        float S = 0.f, Q = 0.f;
#pragma unroll
        for (int s2 = 0; s2 < 16; s2++) {
            S += zsum[layer * 2048 + tid * 16 + s2];
            Q += zsum[layer * 2048 + (64 + tid) * 16 + s2];
        }
        float mean = S * (1.0f / NN);
        float var = Q * (1.0f / NN) - mean * mean;
        float sc = gamma[layer * 64 + tid] * rsqrtf(var + EPS_BN);
        scs[tid] = sc;
        shs[tid] = beta[layer * 64 + tid] - mean * sc;
    }
    __syncthreads();
    int d = blockIdx.x * 8 + g;
    float z0 = z[(size_t)d * 64 + c] * scs[c] + shs[c];
    float z1 = z[(size_t)d * 64 + 32 + c] * scs[c + 32] + shs[c + 32];
    zs[g][c] = fmaxf(z0, 0.f);
    zs[g][c + 32] = fmaxf(z1, 0.f);
    __syncthreads();
    float acc = b2[layer * HID + c];
#pragma unroll
    for (int k = 0; k < 64; k++) acc += zs[g][k] * w2s[k * HID + c];
    float r = fmaxf(acc, 0.f);
    hout[(size_t)d * HID + c] = r;
    __half mv = __float2half(r);                    // relu(h) (h>=0 here)
    if (c < 16) mA[(size_t)d * 16 + c] = mv;
    else        mB[(size_t)d * 16 + (c - 16)] = mv;
}

// ---------------- output projection: out = h @ w16 + b16 ----------------

__global__ __launch_bounds__(256) void k_final(const float* __restrict__ h,
                                               const float* __restrict__ w16,
                                               const float* __restrict__ b16,
                                               float* __restrict__ out) {
    __shared__ float ws[HID * OUT_CH];   // 8 KB
    __shared__ float hs[8][HID];
    int tid = threadIdx.x, c = tid & 31, g = tid >> 5;
    for (int k = tid; k < HID * OUT_CH; k += 256) ws[k] = w16[k];
    int d = blockIdx.x * 8 + g;
    hs[g][c] = h[(size_t)d * HID + c];
    __syncthreads();
    float o0 = b16[c], o1 = b16[c + 32];
#pragma unroll
    for (int k = 0; k < HID; k++) {
        float hv = hs[g][k];
        o0 += hv * ws[k * OUT_CH + c];
        o1 += hv * ws[k * OUT_CH + c + 32];
    }
    out[(size_t)d * OUT_CH + c] = o0;
    out[(size_t)d * OUT_CH + 32 + c] = o1;
}

// ---------------- host ----------------

extern "C" void kernel_launch(void* const* d_in, const int* in_sizes, int n_in,
                              void* d_out, int out_size, void* d_ws, size_t ws_size,
                              hipStream_t stream) {
    const float* x      = (const float*)d_in[0];
    const int*   ei     = (const int*)d_in[1];
    const float* w0     = (const float*)d_in[2];
    const float* b0     = (const float*)d_in[3];
    const float* lin1_w = (const float*)d_in[4];
    const float* lin1_b = (const float*)d_in[5];
    const float* gamma  = (const float*)d_in[6];
    const float* beta   = (const float*)d_in[7];
    const float* lin2_w = (const float*)d_in[8];
    const float* lin2_b = (const float*)d_in[9];
    const float* w16    = (const float*)d_in[10];
    const float* b16    = (const float*)d_in[11];
    float* out = (float*)d_out;

    const int E = in_sizes[1] / 2;
    const int* src = ei;
    const int* dst = ei + E;

    // workspace carve-up (all 256B-aligned)
    char* p = (char*)d_ws;
    auto alloc = [&](size_t bytes) {
        char* q = p;
        p += (bytes + 255) & ~(size_t)255;
        return q;
    };
    float*  hA     = (float*)alloc((size_t)NN * HID * 4);
    float*  hB     = (float*)alloc((size_t)NN * HID * 4);
    __half* mA     = (__half*)alloc((size_t)NN * 16 * 2);   // ch 0-15 messages
    __half* mB     = (__half*)alloc((size_t)NN * 16 * 2);   // ch 16-31 messages
    float*  oA     = (float*)alloc((size_t)NN * 16 * 4);    // agg+res ch 0-15
    float*  oB     = (float*)alloc((size_t)NN * 16 * 4);    // agg+res ch 16-31
    float*  z      = (float*)alloc((size_t)NN * 64 * 4);
    int*    rowptr = (int*)alloc((size_t)(NN + 1) * 4);
    int*    cursor = (int*)alloc((size_t)NN * 4);
    int*    counts = (int*)alloc((size_t)NN * 4);
    int*    col    = (int*)alloc((size_t)(E + 32) * 4);     // +32 pad for windowed reads
    int*    bsum   = (int*)alloc(1024 * 4);
    float*  zsum   = (float*)alloc((size_t)N_LAYERS * 2048 * 4);  // [L][128ch][16 slots]
    (void)ws_size; (void)n_in; (void)out_size;

    // --- zero accumulators + CSR build (once per call; reused by all layers) ---
    hipMemsetAsync(counts, 0, (size_t)NN * 4, stream);
    hipMemsetAsync(zsum, 0, (size_t)N_LAYERS * 2048 * 4, stream);
    hipMemsetAsync(col + E, 0, 32 * 4, stream);   // pad entries -> node 0 (safe loads)
    int egrid = (E + 255) / 256;
    k_hist<<<egrid, 256, 0, stream>>>(dst, counts, E);
    int b1g = (NN + 1023) / 1024;
    k_scan1<<<b1g, 1024, 0, stream>>>(counts, rowptr, bsum, NN);
    k_scan2<<<1, 1, 0, stream>>>(bsum, b1g);
    k_scan3<<<(NN + 255) / 256, 256, 0, stream>>>(rowptr, cursor, bsum, NN, E);
    k_scatter<<<egrid, 256, 0, stream>>>(src, dst, cursor, col, E);

    // --- input projection (+ message precompute) ---
    k0<<<NN / 8, 256, 0, stream>>>(x, w0, b0, hA, mA, mB);

    // --- 16 layers ---
    float* hin = hA;
    float* hout = hB;
    for (int i = 0; i < N_LAYERS; i++) {
        k_aggp<<<NB1, 256, 0, stream>>>(hin, mA, rowptr, col, oA, 0);
        k_aggp<<<NB1, 256, 0, stream>>>(hin, mB, rowptr, col, oB, 16);
        k_lin1<<<NN / 8, 256, 0, stream>>>(oA, oB, lin1_w, lin1_b, z, zsum, i);
        k_bn2<<<NN / 8, 256, 0, stream>>>(z, zsum, gamma, beta, lin2_w, lin2_b, hout, mA, mB, i);
        float* t = hin; hin = hout; hout = t;
    }

    // --- output projection ---
    k_final<<<NN / 8, 256, 0, stream>>>(hin, w16, b16, out);
}

// Round 7
// 2860.326 us; speedup vs baseline: 2.3689x; 2.3689x over previous
//
#include <hip/hip_runtime.h>
#include <hip/hip_fp16.h>

#define NN 100000
#define IN_CH 128
#define HID 32
#define OUT_CH 64
#define N_LAYERS 16
#define NB1 2048            // agg-pass blocks (4 waves each -> 8192 waves)
#define NBM 256             // k_mom blocks
#define EPS_MSG 1e-7f
#define EPS_SM 1e-16f
#define EPS_BN 1e-5f

// ---------------- CSR build ----------------

__global__ void k_hist(const int* __restrict__ dst, int* __restrict__ counts, int E) {
    int i = blockIdx.x * 256 + threadIdx.x;
    if (i < E) atomicAdd(&counts[dst[i]], 1);
}

__global__ void k_scan1(const int* __restrict__ counts, int* __restrict__ rowptr,
                        int* __restrict__ bsum, int n) {
    __shared__ int sh[1024];
    int t = threadIdx.x;
    int i = blockIdx.x * 1024 + t;
    int v = (i < n) ? counts[i] : 0;
    sh[t] = v;
    __syncthreads();
    for (int off = 1; off < 1024; off <<= 1) {
        int tmp = (t >= off) ? sh[t - off] : 0;
        __syncthreads();
        sh[t] += tmp;
        __syncthreads();
    }
    if (i < n) rowptr[i] = sh[t] - v;   // exclusive within chunk
    if (t == 1023) bsum[blockIdx.x] = sh[1023];
}

__global__ void k_scan2(int* __restrict__ bsum, int nb) {
    if (threadIdx.x == 0 && blockIdx.x == 0) {
        int acc = 0;
        for (int b = 0; b < nb; b++) { int v = bsum[b]; bsum[b] = acc; acc += v; }
    }
}

__global__ void k_scan3(int* __restrict__ rowptr, int* __restrict__ cursor,
                        const int* __restrict__ bsum, int n, int E) {
    int i = blockIdx.x * 256 + threadIdx.x;
    if (i < n) {
        int r = rowptr[i] + bsum[i >> 10];
        rowptr[i] = r;
        cursor[i] = r;
    }
    if (i == 0) rowptr[n] = E;
}

__global__ void k_scatter(const int* __restrict__ src, const int* __restrict__ dst,
                          int* __restrict__ cursor, int* __restrict__ col, int E) {
    int i = blockIdx.x * 256 + threadIdx.x;
    if (i < E) {
        int d = dst[i];
        int p = atomicAdd(&cursor[d], 1);
        col[p] = src[i];
    }
}

// ---------------- input projection: h0 = x @ w0 + b0 (+ fp16 chunked messages) ----------------

__global__ __launch_bounds__(256) void k0(const float* __restrict__ x,
                                          const float* __restrict__ w0,
                                          const float* __restrict__ b0,
                                          float* __restrict__ h,
                                          __half* __restrict__ mA,
                                          __half* __restrict__ mB) {
    __shared__ float ws[IN_CH * HID];   // 16 KB
    __shared__ float xs[8][IN_CH];      // 4 KB
    int tid = threadIdx.x, c = tid & 31, g = tid >> 5;
    for (int k = tid; k < IN_CH * HID; k += 256) ws[k] = w0[k];
    int d = blockIdx.x * 8 + g;
    float4 xv = ((const float4*)(x + (size_t)d * IN_CH))[c];
    ((float4*)xs[g])[c] = xv;
    __syncthreads();
    float acc = b0[c];
#pragma unroll 16
    for (int k = 0; k < IN_CH; k++) acc += xs[g][k] * ws[k * HID + c];
    h[(size_t)d * HID + c] = acc;
    __half mv = __float2half(fmaxf(acc, 0.f));      // relu(h); +eps added at gather
    if (c < 16) mA[(size_t)d * 16 + c] = mv;
    else        mB[(size_t)d * 16 + (c - 16)] = mv;
}

// ---------------- softmax-agg pass over ONE 16-channel chunk ----------------
// One node per full wave: 64 lanes = 16 channels x 4 edge-slots. The gathered
// array mc is 3.2 MB -> resident in each XCD's 4 MB L2 (confirmed R6: ~27 us).

__global__ __launch_bounds__(256, 8) void k_aggp(const float* __restrict__ h,
                                                 const __half* __restrict__ mc,
                                                 const int* __restrict__ rowptr,
                                                 const int* __restrict__ col,
                                                 float* __restrict__ oc,
                                                 int coff) {
    int tid = threadIdx.x;
    int lane = tid & 63;
    int c = lane & 15;                     // channel within chunk
    int eslot = lane >> 4;                 // 0..3: edge sub-slot
    int wid = (blockIdx.x * 256 + tid) >> 6;
    const int nwaves = NB1 * 4;

    for (int d = wid; d < NN; d += nwaves) {
        int r0 = rowptr[d], r1 = rowptr[d + 1];   // wave-uniform -> scalar loads
        float den = 0.f, num = 0.f;
        for (int e0 = r0; e0 < r1; e0 += 32) {
            int colw = col[e0 + (lane & 31)];     // 32-edge window, coalesced
            int nb = r1 - e0; if (nb > 32) nb = 32;
            float vv[8];
#pragma unroll
            for (int j = 0; j < 8; j++) {         // 8 instrs x 4 edges in flight
                int s = __shfl(colw, j * 4 + eslot, 64);
                vv[j] = __half2float(mc[(size_t)s * 16 + c]);
            }
#pragma unroll
            for (int j = 0; j < 8; j++) {
                float v = vv[j] + EPS_MSG;
                float ev = __expf(v);             // bounded: no max-subtraction
                bool ok = (j * 4 + eslot) < nb;
                den += ok ? ev : 0.f;
                num += ok ? ev * v : 0.f;
            }
        }
        // reduce across the 4 edge-slots (lanes c, c+16, c+32, c+48)
        den += __shfl_xor(den, 16, 64); num += __shfl_xor(num, 16, 64);
        den += __shfl_xor(den, 32, 64); num += __shfl_xor(num, 32, 64);
        if (eslot == 0) {
            float res = h[(size_t)d * HID + coff + c];
            oc[(size_t)d * 16 + c] = num / (den + EPS_SM) + res;
        }
    }
}

// ---------------- moment accumulation: sums of out (32) + out outer-prod (528) ----------------
// Per-block register accumulation -> per-block partials. ZERO atomics (R6's
// 346us k_lin1 was 1.6M same-word HBM atomics).

__device__ __forceinline__ void mom_decode(int v, int& i, int& j) {
    if (v < 32) { i = -1; j = v; return; }     // mean slot
    int p = v - 32, ii = 0;
    while (p >= 32 - ii) { p -= 32 - ii; ii++; }
    i = ii; j = ii + p;                        // pair (i<=j)
}

__global__ __launch_bounds__(256) void k_mom(const float* __restrict__ oA,
                                             const float* __restrict__ oB,
                                             float* __restrict__ momp) {
    __shared__ float outs[8][32];
    int tid = threadIdx.x, c = tid & 31, g = tid >> 5;
    int i0, j0, i1, j1, i2, j2;
    mom_decode(tid, i0, j0);
    mom_decode(tid + 256, i1, j1);
    bool has2 = (tid + 512) < 560;
    mom_decode(has2 ? tid + 512 : 32, i2, j2);
    float a0 = 0.f, a1 = 0.f, a2 = 0.f;

    for (int d0 = blockIdx.x * 8; d0 < NN; d0 += NBM * 8) {
        int d = d0 + g;
        outs[g][c] = (c < 16) ? oA[(size_t)d * 16 + c] : oB[(size_t)d * 16 + (c - 16)];
        __syncthreads();
#pragma unroll
        for (int g2 = 0; g2 < 8; g2++) {
            a0 += (i0 < 0) ? outs[g2][j0] : outs[g2][i0] * outs[g2][j0];
            a1 += (i1 < 0) ? outs[g2][j1] : outs[g2][i1] * outs[g2][j1];
            a2 += (i2 < 0) ? outs[g2][j2] : outs[g2][i2] * outs[g2][j2];
        }
        __syncthreads();
    }
    momp[(size_t)blockIdx.x * 560 + tid] = a0;
    momp[(size_t)blockIdx.x * 560 + 256 + tid] = a1;
    if (has2) momp[(size_t)blockIdx.x * 560 + 512 + tid] = a2;
}

// ---------------- moment reduce -> BN scale/shift (1 block) ----------------

__global__ __launch_bounds__(1024) void k_momred(const float* __restrict__ momp,
                                                 const float* __restrict__ w1,
                                                 const float* __restrict__ b1,
                                                 const float* __restrict__ gamma,
                                                 const float* __restrict__ beta,
                                                 float* __restrict__ bnsc,
                                                 float* __restrict__ bnsh,
                                                 int layer) {
    __shared__ double dmom[560];
    __shared__ float C[32][32];
    __shared__ float mo[32];
    __shared__ float ws[2048];
    int tid = threadIdx.x;
    for (int k = tid; k < 2048; k += 1024) ws[k] = w1[layer * 2048 + k];
    if (tid < 560) {
        double s = 0.0;
        for (int b = 0; b < NBM; b++) s += (double)momp[(size_t)b * 560 + tid];
        dmom[tid] = s;
    }
    __syncthreads();
    if (tid < 32) mo[tid] = (float)(dmom[tid] / (double)NN);
    __syncthreads();
    {
        int i = tid >> 5, k = tid & 31;
        int lo = i < k ? i : k, hi = i < k ? k : i;
        int p = 32 * lo - (lo * (lo - 1)) / 2 + (hi - lo);
        C[i][k] = (float)(dmom[32 + p] / (double)NN) - mo[i] * mo[k];
    }
    __syncthreads();
    if (tid < 64) {
        float mu = b1[layer * 64 + tid];
        float var = 0.f;
        for (int i = 0; i < 32; i++) {
            float wi = ws[i * 64 + tid];
            mu += mo[i] * wi;
            float acc = 0.f;
            for (int k = 0; k < 32; k++) acc += ws[k * 64 + tid] * C[i][k];
            var += wi * acc;
        }
        var = fmaxf(var, 0.f);
        float sc = gamma[layer * 64 + tid] * rsqrtf(var + EPS_BN);
        bnsc[tid] = sc;
        bnsh[tid] = beta[layer * 64 + tid] - mu * sc;
    }
}

// ---------------- fused lin1 + BN + relu + lin2 + relu (+ fp16 messages) ----------------
// z is never materialized: saves 51 MB/layer of HBM traffic.

__global__ __launch_bounds__(256) void k_fused(const float* __restrict__ oA,
                                               const float* __restrict__ oB,
                                               const float* __restrict__ w1,
                                               const float* __restrict__ b1,
                                               const float* __restrict__ bnsc,
                                               const float* __restrict__ bnsh,
                                               const float* __restrict__ w2,
                                               const float* __restrict__ b2,
                                               float* __restrict__ hout,
                                               __half* __restrict__ mA,
                                               __half* __restrict__ mB,
                                               int layer) {
    __shared__ float w1s[HID * 64];   // 8 KB
    __shared__ float w2s[64 * HID];   // 8 KB
    __shared__ float outs[8][HID];
    __shared__ float zs[8][64];
    __shared__ float b1s[64], scs[64], shs[64];
    int tid = threadIdx.x, c = tid & 31, g = tid >> 5;
    for (int k = tid; k < HID * 64; k += 256) w1s[k] = w1[layer * (HID * 64) + k];
    for (int k = tid; k < 64 * HID; k += 256) w2s[k] = w2[layer * (64 * HID) + k];
    if (tid < 64) { b1s[tid] = b1[layer * 64 + tid]; scs[tid] = bnsc[tid]; shs[tid] = bnsh[tid]; }
    int d = blockIdx.x * 8 + g;
    outs[g][c] = (c < 16) ? oA[(size_t)d * 16 + c] : oB[(size_t)d * 16 + (c - 16)];
    __syncthreads();
    float z0 = b1s[c], z1 = b1s[c + 32];
#pragma unroll
    for (int k = 0; k < HID; k++) {
        float o = outs[g][k];
        z0 += o * w1s[k * 64 + c];
        z1 += o * w1s[k * 64 + c + 32];
    }
    zs[g][c] = fmaxf(z0 * scs[c] + shs[c], 0.f);
    zs[g][c + 32] = fmaxf(z1 * scs[c + 32] + shs[c + 32], 0.f);
    __syncthreads();
    float acc = b2[layer * HID + c];
#pragma unroll
    for (int k = 0; k < 64; k++) acc += zs[g][k] * w2s[k * HID + c];
    float r = fmaxf(acc, 0.f);
    hout[(size_t)d * HID + c] = r;
    __half mv = __float2half(r);                    // relu(h) (h>=0 here)
    if (c < 16) mA[(size_t)d * 16 + c] = mv;
    else        mB[(size_t)d * 16 + (c - 16)] = mv;
}

// ---------------- output projection: out = h @ w16 + b16 ----------------

__global__ __launch_bounds__(256) void k_final(const float* __restrict__ h,
                                               const float* __restrict__ w16,
                                               const float* __restrict__ b16,
                                               float* __restrict__ out) {
    __shared__ float ws[HID * OUT_CH];   // 8 KB
    __shared__ float hs[8][HID];
    int tid = threadIdx.x, c = tid & 31, g = tid >> 5;
    for (int k = tid; k < HID * OUT_CH; k += 256) ws[k] = w16[k];
    int d = blockIdx.x * 8 + g;
    hs[g][c] = h[(size_t)d * HID + c];
    __syncthreads();
    float o0 = b16[c], o1 = b16[c + 32];
#pragma unroll
    for (int k = 0; k < HID; k++) {
        float hv = hs[g][k];
        o0 += hv * ws[k * OUT_CH + c];
        o1 += hv * ws[k * OUT_CH + c + 32];
    }
    out[(size_t)d * OUT_CH + c] = o0;
    out[(size_t)d * OUT_CH + 32 + c] = o1;
}

// ---------------- host ----------------

extern "C" void kernel_launch(void* const* d_in, const int* in_sizes, int n_in,
                              void* d_out, int out_size, void* d_ws, size_t ws_size,
                              hipStream_t stream) {
    const float* x      = (const float*)d_in[0];
    const int*   ei     = (const int*)d_in[1];
    const float* w0     = (const float*)d_in[2];
    const float* b0     = (const float*)d_in[3];
    const float* lin1_w = (const float*)d_in[4];
    const float* lin1_b = (const float*)d_in[5];
    const float* gamma  = (const float*)d_in[6];
    const float* beta   = (const float*)d_in[7];
    const float* lin2_w = (const float*)d_in[8];
    const float* lin2_b = (const float*)d_in[9];
    const float* w16    = (const float*)d_in[10];
    const float* b16    = (const float*)d_in[11];
    float* out = (float*)d_out;

    const int E = in_sizes[1] / 2;
    const int* src = ei;
    const int* dst = ei + E;

    // workspace carve-up (all 256B-aligned)
    char* p = (char*)d_ws;
    auto alloc = [&](size_t bytes) {
        char* q = p;
        p += (bytes + 255) & ~(size_t)255;
        return q;
    };
    float*  hA     = (float*)alloc((size_t)NN * HID * 4);
    float*  hB     = (float*)alloc((size_t)NN * HID * 4);
    __half* mA     = (__half*)alloc((size_t)NN * 16 * 2);   // ch 0-15 messages
    __half* mB     = (__half*)alloc((size_t)NN * 16 * 2);   // ch 16-31 messages
    float*  oA     = (float*)alloc((size_t)NN * 16 * 4);    // agg+res ch 0-15
    float*  oB     = (float*)alloc((size_t)NN * 16 * 4);    // agg+res ch 16-31
    int*    rowptr = (int*)alloc((size_t)(NN + 1) * 4);
    int*    cursor = (int*)alloc((size_t)NN * 4);
    int*    counts = (int*)alloc((size_t)NN * 4);
    int*    col    = (int*)alloc((size_t)(E + 32) * 4);     // +32 pad for windowed reads
    int*    bsum   = (int*)alloc(1024 * 4);
    float*  momp   = (float*)alloc((size_t)NBM * 560 * 4);  // per-block moment partials
    float*  bnsc   = (float*)alloc(64 * 4);
    float*  bnsh   = (float*)alloc(64 * 4);
    (void)ws_size; (void)n_in; (void)out_size;

    // --- CSR build (once per call; reused by all layers) ---
    hipMemsetAsync(counts, 0, (size_t)NN * 4, stream);
    hipMemsetAsync(col + E, 0, 32 * 4, stream);   // pad entries -> node 0 (safe loads)
    int egrid = (E + 255) / 256;
    k_hist<<<egrid, 256, 0, stream>>>(dst, counts, E);
    int b1g = (NN + 1023) / 1024;
    k_scan1<<<b1g, 1024, 0, stream>>>(counts, rowptr, bsum, NN);
    k_scan2<<<1, 1, 0, stream>>>(bsum, b1g);
    k_scan3<<<(NN + 255) / 256, 256, 0, stream>>>(rowptr, cursor, bsum, NN, E);
    k_scatter<<<egrid, 256, 0, stream>>>(src, dst, cursor, col, E);

    // --- input projection (+ message precompute) ---
    k0<<<NN / 8, 256, 0, stream>>>(x, w0, b0, hA, mA, mB);

    // --- 16 layers ---
    float* hin = hA;
    float* hout = hB;
    for (int i = 0; i < N_LAYERS; i++) {
        k_aggp<<<NB1, 256, 0, stream>>>(hin, mA, rowptr, col, oA, 0);
        k_aggp<<<NB1, 256, 0, stream>>>(hin, mB, rowptr, col, oB, 16);
        k_mom<<<NBM, 256, 0, stream>>>(oA, oB, momp);
        k_momred<<<1, 1024, 0, stream>>>(momp, lin1_w, lin1_b, gamma, beta, bnsc, bnsh, i);
        k_fused<<<NN / 8, 256, 0, stream>>>(oA, oB, lin1_w, lin1_b, bnsc, bnsh,
                                            lin2_w, lin2_b, hout, mA, mB, i);
        float* t = hin; hin = hout; hout = t;
    }

    // --- output projection ---
    k_final<<<NN / 8, 256, 0, stream>>>(hin, w16, b16, out);
}

// Round 8
// 2569.371 us; speedup vs baseline: 2.6371x; 1.1132x over previous
//
#include <hip/hip_runtime.h>
#include <hip/hip_fp16.h>

#define NN 100000
#define IN_CH 128
#define HID 32
#define OUT_CH 64
#define N_LAYERS 16
#define NB1 2048            // agg-pass blocks (4 waves each -> 8192 waves)
#define NBM 2048            // k_mom blocks (short latency chains)
#define EPS_MSG 1e-7f
#define EPS_SM 1e-16f
#define EPS_BN 1e-5f

// ---------------- CSR build ----------------

__global__ void k_hist(const int* __restrict__ dst, int* __restrict__ counts, int E) {
    int i = blockIdx.x * 256 + threadIdx.x;
    if (i < E) atomicAdd(&counts[dst[i]], 1);
}

__global__ void k_scan1(const int* __restrict__ counts, int* __restrict__ rowptr,
                        int* __restrict__ bsum, int n) {
    __shared__ int sh[1024];
    int t = threadIdx.x;
    int i = blockIdx.x * 1024 + t;
    int v = (i < n) ? counts[i] : 0;
    sh[t] = v;
    __syncthreads();
    for (int off = 1; off < 1024; off <<= 1) {
        int tmp = (t >= off) ? sh[t - off] : 0;
        __syncthreads();
        sh[t] += tmp;
        __syncthreads();
    }
    if (i < n) rowptr[i] = sh[t] - v;   // exclusive within chunk
    if (t == 1023) bsum[blockIdx.x] = sh[1023];
}

__global__ void k_scan2(int* __restrict__ bsum, int nb) {
    if (threadIdx.x == 0 && blockIdx.x == 0) {
        int acc = 0;
        for (int b = 0; b < nb; b++) { int v = bsum[b]; bsum[b] = acc; acc += v; }
    }
}

__global__ void k_scan3(int* __restrict__ rowptr, int* __restrict__ cursor,
                        const int* __restrict__ bsum, int n, int E) {
    int i = blockIdx.x * 256 + threadIdx.x;
    if (i < n) {
        int r = rowptr[i] + bsum[i >> 10];
        rowptr[i] = r;
        cursor[i] = r;
    }
    if (i == 0) rowptr[n] = E;
}

__global__ void k_scatter(const int* __restrict__ src, const int* __restrict__ dst,
                          int* __restrict__ cursor, int* __restrict__ col, int E) {
    int i = blockIdx.x * 256 + threadIdx.x;
    if (i < E) {
        int d = dst[i];
        int p = atomicAdd(&cursor[d], 1);
        col[p] = src[i];
    }
}

// ---------------- input projection: h0 = x @ w0 + b0 (+ fp16 chunked messages) ----------------

__global__ __launch_bounds__(256) void k0(const float* __restrict__ x,
                                          const float* __restrict__ w0,
                                          const float* __restrict__ b0,
                                          float* __restrict__ h,
                                          __half* __restrict__ mA,
                                          __half* __restrict__ mB) {
    __shared__ float ws[IN_CH * HID];   // 16 KB
    __shared__ float xs[8][IN_CH];      // 4 KB
    int tid = threadIdx.x, c = tid & 31, g = tid >> 5;
    for (int k = tid; k < IN_CH * HID; k += 256) ws[k] = w0[k];
    int d = blockIdx.x * 8 + g;
    float4 xv = ((const float4*)(x + (size_t)d * IN_CH))[c];
    ((float4*)xs[g])[c] = xv;
    __syncthreads();
    float acc = b0[c];
#pragma unroll 16
    for (int k = 0; k < IN_CH; k++) acc += xs[g][k] * ws[k * HID + c];
    h[(size_t)d * HID + c] = acc;
    __half mv = __float2half(fmaxf(acc, 0.f));      // relu(h); +eps added at gather
    if (c < 16) mA[(size_t)d * 16 + c] = mv;
    else        mB[(size_t)d * 16 + (c - 16)] = mv;
}

// ---------------- softmax-agg pass over ONE 16-channel chunk ----------------
// One node per full wave: 64 lanes = 16 channels x 4 edge-slots. The gathered
// array mc is 3.2 MB -> resident in each XCD's 4 MB L2 (confirmed R6/R7).

__global__ __launch_bounds__(256, 8) void k_aggp(const float* __restrict__ h,
                                                 const __half* __restrict__ mc,
                                                 const int* __restrict__ rowptr,
                                                 const int* __restrict__ col,
                                                 float* __restrict__ oc,
                                                 int coff) {
    int tid = threadIdx.x;
    int lane = tid & 63;
    int c = lane & 15;                     // channel within chunk
    int eslot = lane >> 4;                 // 0..3: edge sub-slot
    int wid = (blockIdx.x * 256 + tid) >> 6;
    const int nwaves = NB1 * 4;

    for (int d = wid; d < NN; d += nwaves) {
        int r0 = rowptr[d], r1 = rowptr[d + 1];   // wave-uniform -> scalar loads
        float den = 0.f, num = 0.f;
        for (int e0 = r0; e0 < r1; e0 += 32) {
            int colw = col[e0 + (lane & 31)];     // 32-edge window, coalesced
            int nb = r1 - e0; if (nb > 32) nb = 32;
            float vv[8];
#pragma unroll
            for (int j = 0; j < 8; j++) {         // 8 instrs x 4 edges in flight
                int s = __shfl(colw, j * 4 + eslot, 64);
                vv[j] = __half2float(mc[(size_t)s * 16 + c]);
            }
#pragma unroll
            for (int j = 0; j < 8; j++) {
                float v = vv[j] + EPS_MSG;
                float ev = __expf(v);             // bounded: no max-subtraction
                bool ok = (j * 4 + eslot) < nb;
                den += ok ? ev : 0.f;
                num += ok ? ev * v : 0.f;
            }
        }
        // reduce across the 4 edge-slots (lanes c, c+16, c+32, c+48)
        den += __shfl_xor(den, 16, 64); num += __shfl_xor(num, 16, 64);
        den += __shfl_xor(den, 32, 64); num += __shfl_xor(num, 32, 64);
        if (eslot == 0) {
            float res = h[(size_t)d * HID + coff + c];
            oc[(size_t)d * 16 + c] = num / (den + EPS_SM) + res;
        }
    }
}

// ---------------- moment accumulation: sums of out (32) + outer-prod (528) ----------------
// 2048 blocks: each has a SHORT latency chain (~7 iterations). Zero atomics.

__device__ __forceinline__ void mom_decode(int v, int& i, int& j) {
    if (v < 32) { i = -1; j = v; return; }     // mean slot
    int p = v - 32, ii = 0;
    while (p >= 32 - ii) { p -= 32 - ii; ii++; }
    i = ii; j = ii + p;                        // pair (i<=j)
}

__global__ __launch_bounds__(256) void k_mom(const float* __restrict__ oA,
                                             const float* __restrict__ oB,
                                             float* __restrict__ momp) {
    __shared__ float outs[8][32];
    int tid = threadIdx.x, c = tid & 31, g = tid >> 5;
    int i0, j0, i1, j1, i2, j2;
    mom_decode(tid, i0, j0);
    mom_decode(tid + 256, i1, j1);
    bool has2 = (tid + 512) < 560;
    mom_decode(has2 ? tid + 512 : 32, i2, j2);
    float a0 = 0.f, a1 = 0.f, a2 = 0.f;

    for (int d0 = blockIdx.x * 8; d0 < NN; d0 += NBM * 8) {
        int d = d0 + g;
        float v = 0.f;
        if (d < NN) v = (c < 16) ? oA[(size_t)d * 16 + c] : oB[(size_t)d * 16 + (c - 16)];
        outs[g][c] = v;
        __syncthreads();
#pragma unroll
        for (int g2 = 0; g2 < 8; g2++) {
            a0 += (i0 < 0) ? outs[g2][j0] : outs[g2][i0] * outs[g2][j0];
            a1 += (i1 < 0) ? outs[g2][j1] : outs[g2][i1] * outs[g2][j1];
            a2 += (i2 < 0) ? outs[g2][j2] : outs[g2][i2] * outs[g2][j2];
        }
        __syncthreads();
    }
    momp[(size_t)blockIdx.x * 560 + tid] = a0;
    momp[(size_t)blockIdx.x * 560 + 256 + tid] = a1;
    if (has2) momp[(size_t)blockIdx.x * 560 + 512 + tid] = a2;
}

// ---------------- parallel partial reduce: 560 blocks, one slot each ----------------

__global__ __launch_bounds__(256) void k_red1(const float* __restrict__ momp,
                                              double* __restrict__ dmomg) {
    __shared__ double sh[256];
    int slot = blockIdx.x;
    int t = threadIdx.x;
    double s = 0.0;
#pragma unroll
    for (int k = 0; k < 8; k++)                       // 8 independent loads in flight
        s += (double)momp[(size_t)(t + 256 * k) * 560 + slot];
    sh[t] = s;
    __syncthreads();
    for (int off = 128; off > 0; off >>= 1) {
        if (t < off) sh[t] += sh[t + off];
        __syncthreads();
    }
    if (t == 0) dmomg[slot] = sh[0];
}

// ---------------- moments -> BN scale/shift via covariance (1 tiny block) ----------------

__global__ __launch_bounds__(1024) void k_momred(const double* __restrict__ dmomg,
                                                 const float* __restrict__ w1,
                                                 const float* __restrict__ b1,
                                                 const float* __restrict__ gamma,
                                                 const float* __restrict__ beta,
                                                 float* __restrict__ bnsc,
                                                 float* __restrict__ bnsh,
                                                 int layer) {
    __shared__ float C[32][32];
    __shared__ float mo[32];
    __shared__ float ws[2048];
    int tid = threadIdx.x;
    for (int k = tid; k < 2048; k += 1024) ws[k] = w1[layer * 2048 + k];
    if (tid < 32) mo[tid] = (float)(dmomg[tid] / (double)NN);
    __syncthreads();
    {
        int i = tid >> 5, k = tid & 31;
        int lo = i < k ? i : k, hi = i < k ? k : i;
        int p = 32 * lo - (lo * (lo - 1)) / 2 + (hi - lo);
        C[i][k] = (float)(dmomg[32 + p] / (double)NN) - mo[i] * mo[k];
    }
    __syncthreads();
    if (tid < 64) {
        float mu = b1[layer * 64 + tid];
        float var = 0.f;
        for (int i = 0; i < 32; i++) {
            float wi = ws[i * 64 + tid];
            mu += mo[i] * wi;
            float acc = 0.f;
            for (int k = 0; k < 32; k++) acc += ws[k * 64 + tid] * C[i][k];
            var += wi * acc;
        }
        var = fmaxf(var, 0.f);
        float sc = gamma[layer * 64 + tid] * rsqrtf(var + EPS_BN);
        bnsc[tid] = sc;
        bnsh[tid] = beta[layer * 64 + tid] - mu * sc;
    }
}

// ---------------- fused lin1 + BN + relu + lin2 + relu (+ fp16 messages) ----------------

__global__ __launch_bounds__(256) void k_fused(const float* __restrict__ oA,
                                               const float* __restrict__ oB,
                                               const float* __restrict__ w1,
                                               const float* __restrict__ b1,
                                               const float* __restrict__ bnsc,
                                               const float* __restrict__ bnsh,
                                               const float* __restrict__ w2,
                                               const float* __restrict__ b2,
                                               float* __restrict__ hout,
                                               __half* __restrict__ mA,
                                               __half* __restrict__ mB,
                                               int layer) {
    __shared__ float w1s[HID * 64];   // 8 KB
    __shared__ float w2s[64 * HID];   // 8 KB
    __shared__ float outs[8][HID];
    __shared__ float zs[8][64];
    __shared__ float b1s[64], scs[64], shs[64];
    int tid = threadIdx.x, c = tid & 31, g = tid >> 5;
    for (int k = tid; k < HID * 64; k += 256) w1s[k] = w1[layer * (HID * 64) + k];
    for (int k = tid; k < 64 * HID; k += 256) w2s[k] = w2[layer * (64 * HID) + k];
    if (tid < 64) { b1s[tid] = b1[layer * 64 + tid]; scs[tid] = bnsc[tid]; shs[tid] = bnsh[tid]; }
    int d = blockIdx.x * 8 + g;
    outs[g][c] = (c < 16) ? oA[(size_t)d * 16 + c] : oB[(size_t)d * 16 + (c - 16)];
    __syncthreads();
    float z0 = b1s[c], z1 = b1s[c + 32];
#pragma unroll
    for (int k = 0; k < HID; k++) {
        float o = outs[g][k];
        z0 += o * w1s[k * 64 + c];
        z1 += o * w1s[k * 64 + c + 32];
    }
    zs[g][c] = fmaxf(z0 * scs[c] + shs[c], 0.f);
    zs[g][c + 32] = fmaxf(z1 * scs[c + 32] + shs[c + 32], 0.f);
    __syncthreads();
    float acc = b2[layer * HID + c];
#pragma unroll
    for (int k = 0; k < 64; k++) acc += zs[g][k] * w2s[k * HID + c];
    float r = fmaxf(acc, 0.f);
    hout[(size_t)d * HID + c] = r;
    __half mv = __float2half(r);                    // relu(h) (h>=0 here)
    if (c < 16) mA[(size_t)d * 16 + c] = mv;
    else        mB[(size_t)d * 16 + (c - 16)] = mv;
}

// ---------------- output projection: out = h @ w16 + b16 ----------------

__global__ __launch_bounds__(256) void k_final(const float* __restrict__ h,
                                               const float* __restrict__ w16,
                                               const float* __restrict__ b16,
                                               float* __restrict__ out) {
    __shared__ float ws[HID * OUT_CH];   // 8 KB
    __shared__ float hs[8][HID];
    int tid = threadIdx.x, c = tid & 31, g = tid >> 5;
    for (int k = tid; k < HID * OUT_CH; k += 256) ws[k] = w16[k];
    int d = blockIdx.x * 8 + g;
    hs[g][c] = h[(size_t)d * HID + c];
    __syncthreads();
    float o0 = b16[c], o1 = b16[c + 32];
#pragma unroll
    for (int k = 0; k < HID; k++) {
        float hv = hs[g][k];
        o0 += hv * ws[k * OUT_CH + c];
        o1 += hv * ws[k * OUT_CH + c + 32];
    }
    out[(size_t)d * OUT_CH + c] = o0;
    out[(size_t)d * OUT_CH + 32 + c] = o1;
}

// ---------------- host ----------------

extern "C" void kernel_launch(void* const* d_in, const int* in_sizes, int n_in,
                              void* d_out, int out_size, void* d_ws, size_t ws_size,
                              hipStream_t stream) {
    const float* x      = (const float*)d_in[0];
    const int*   ei     = (const int*)d_in[1];
    const float* w0     = (const float*)d_in[2];
    const float* b0     = (const float*)d_in[3];
    const float* lin1_w = (const float*)d_in[4];
    const float* lin1_b = (const float*)d_in[5];
    const float* gamma  = (const float*)d_in[6];
    const float* beta   = (const float*)d_in[7];
    const float* lin2_w = (const float*)d_in[8];
    const float* lin2_b = (const float*)d_in[9];
    const float* w16    = (const float*)d_in[10];
    const float* b16    = (const float*)d_in[11];
    float* out = (float*)d_out;

    const int E = in_sizes[1] / 2;
    const int* src = ei;
    const int* dst = ei + E;

    // workspace carve-up (all 256B-aligned)
    char* p = (char*)d_ws;
    auto alloc = [&](size_t bytes) {
        char* q = p;
        p += (bytes + 255) & ~(size_t)255;
        return q;
    };
    float*  hA     = (float*)alloc((size_t)NN * HID * 4);
    float*  hB     = (float*)alloc((size_t)NN * HID * 4);
    __half* mA     = (__half*)alloc((size_t)NN * 16 * 2);   // ch 0-15 messages
    __half* mB     = (__half*)alloc((size_t)NN * 16 * 2);   // ch 16-31 messages
    float*  oA     = (float*)alloc((size_t)NN * 16 * 4);    // agg+res ch 0-15
    float*  oB     = (float*)alloc((size_t)NN * 16 * 4);    // agg+res ch 16-31
    int*    rowptr = (int*)alloc((size_t)(NN + 1) * 4);
    int*    cursor = (int*)alloc((size_t)NN * 4);
    int*    counts = (int*)alloc((size_t)NN * 4);
    int*    col    = (int*)alloc((size_t)(E + 32) * 4);     // +32 pad for windowed reads
    int*    bsum   = (int*)alloc(1024 * 4);
    float*  momp   = (float*)alloc((size_t)NBM * 560 * 4);  // per-block moment partials
    double* dmomg  = (double*)alloc(560 * 8);
    float*  bnsc   = (float*)alloc(64 * 4);
    float*  bnsh   = (float*)alloc(64 * 4);
    (void)ws_size; (void)n_in; (void)out_size;

    // --- CSR build (once per call; reused by all layers) ---
    hipMemsetAsync(counts, 0, (size_t)NN * 4, stream);
    hipMemsetAsync(col + E, 0, 32 * 4, stream);   // pad entries -> node 0 (safe loads)
    int egrid = (E + 255) / 256;
    k_hist<<<egrid, 256, 0, stream>>>(dst, counts, E);
    int b1g = (NN + 1023) / 1024;
    k_scan1<<<b1g, 1024, 0, stream>>>(counts, rowptr, bsum, NN);
    k_scan2<<<1, 1, 0, stream>>>(bsum, b1g);
    k_scan3<<<(NN + 255) / 256, 256, 0, stream>>>(rowptr, cursor, bsum, NN, E);
    k_scatter<<<egrid, 256, 0, stream>>>(src, dst, cursor, col, E);

    // --- input projection (+ message precompute) ---
    k0<<<NN / 8, 256, 0, stream>>>(x, w0, b0, hA, mA, mB);

    // --- 16 layers ---
    float* hin = hA;
    float* hout = hB;
    for (int i = 0; i < N_LAYERS; i++) {
        k_aggp<<<NB1, 256, 0, stream>>>(hin, mA, rowptr, col, oA, 0);
        k_aggp<<<NB1, 256, 0, stream>>>(hin, mB, rowptr, col, oB, 16);
        k_mom<<<NBM, 256, 0, stream>>>(oA, oB, momp);
        k_red1<<<560, 256, 0, stream>>>(momp, dmomg);
        k_momred<<<1, 1024, 0, stream>>>(dmomg, lin1_w, lin1_b, gamma, beta, bnsc, bnsh, i);
        k_fused<<<NN / 8, 256, 0, stream>>>(oA, oB, lin1_w, lin1_b, bnsc, bnsh,
                                            lin2_w, lin2_b, hout, mA, mB, i);
        float* t = hin; hin = hout; hout = t;
    }

    // --- output projection ---
    k_final<<<NN / 8, 256, 0, stream>>>(hin, w16, b16, out);
}